// Round 1
// baseline (89.335 us; speedup 1.0000x reference)
//
#include <hip/hip_runtime.h>

// Problem dims (fixed by reference): B=32, S=64, E=256, H=4, D=64
constexpr int ED = 256;    // embedding dim
constexpr int SD = 64;     // seq len
constexpr int BD = 32;     // batch
constexpr int NROWS = BD * SD;  // 2048 rows of (E)

typedef _Float16 half8 __attribute__((ext_vector_type(8)));
typedef float floatx4 __attribute__((ext_vector_type(4)));

__device__ inline unsigned short f2h(float f) {   // fp32 -> fp16 bits (RNE)
  union { _Float16 h; unsigned short u; } c;
  c.h = (_Float16)f;
  return c.u;
}

// ---------------------------------------------------------------------------
// Kernel A (prep): 256 blocks.
//  blocks 0..127 : B-fragment-swizzled fp16 exp(W) for the 4 weight matrices.
//    B[k][n] = exp(W[n][k]); frag layout for mfma_f32_16x16x32 (lane l:
//    n = l&15, k = 32*kk + 8*(l>>4) + jj): ushort idx = (kk*256+n)*32 + kl.
//  blocks 128..255: x staging — per 16-row m-tile, rowmax MX[row] and
//    exp(x-rowmax) in A-frag-swizzled fp16 XS (old qkv prologue, hoisted:
//    computed once instead of once per head, and fills the CUs that were
//    idle during the old 128-block expT kernel).
// ---------------------------------------------------------------------------
__global__ __launch_bounds__(256) void prep_kernel(
    const float* __restrict__ x,
    const float* __restrict__ Wq, const float* __restrict__ Wk,
    const float* __restrict__ Wv, const float* __restrict__ Wo,
    unsigned short* __restrict__ EqS, unsigned short* __restrict__ EkS,
    unsigned short* __restrict__ EvS, unsigned short* __restrict__ EoS,
    unsigned short* __restrict__ XS, float* __restrict__ MX)
{
  int bid = blockIdx.x;
  int t = threadIdx.x;
  if (bid < 128) {
    int z = bid >> 5;        // which matrix
    int bx = bid & 31;
    const float* W = (z == 0) ? Wq : (z == 1) ? Wk : (z == 2) ? Wv : Wo;
    unsigned short* out = (z == 0) ? EqS : (z == 1) ? EkS : (z == 2) ? EvS : EoS;
    int n = bx * 8 + (t >> 5), kl = t & 31;
#pragma unroll
    for (int kk = 0; kk < 8; ++kk)
      out[(kk * 256 + n) * 32 + kl] = f2h(__expf(W[n * ED + 32 * kk + kl]));
  } else {
    int mt = bid - 128;                 // m-tile: rows mt*16 .. mt*16+15
    int w = t >> 6, lane = t & 63;
#pragma unroll
    for (int i = 0; i < 4; ++i) {
      int r = 4 * w + i;
      int row = mt * 16 + r;
      float4 xv = *(const float4*)&x[(size_t)row * ED + lane * 4];
      float m = fmaxf(fmaxf(xv.x, xv.y), fmaxf(xv.z, xv.w));
#pragma unroll
      for (int off = 32; off > 0; off >>= 1) m = fmaxf(m, __shfl_xor(m, off));
      ushort4 pk;
      pk.x = f2h(__expf(xv.x - m));
      pk.y = f2h(__expf(xv.y - m));
      pk.z = f2h(__expf(xv.z - m));
      pk.w = f2h(__expf(xv.w - m));
      int k0 = lane * 4;                // kk=k0>>5, q=(k0>>3)&3, jj=k0&7
      int idx = (k0 >> 5) * 512 + ((k0 >> 3) & 3) * 128 + r * 8 + (k0 & 7);
      *(ushort4*)&XS[mt * 4096 + idx] = pk;
      if (lane == 0) MX[row] = m;
    }
  }
}

// ---------------------------------------------------------------------------
// Kernel B: MFMA qkv. Block = 4 waves = M-tile 16 rows x one head (64 cols).
// grid 512 = 128 m-tiles x 4 heads (2 blocks/CU). A-fragments now come
// pre-exp'd and pre-swizzled from XS (global, L2-hot) — no prologue, no
// aswz LDS, one fewer __syncthreads before the MFMAs.
// Epilogue: fused 64-wide softmax(q+k); writes attn in A-frag-swizzled fp16
// (AS) and v in B-frag-swizzled fp16 (VS).
// ---------------------------------------------------------------------------
__global__ __launch_bounds__(256, 2) void qkv_mfma_kernel(
    const unsigned short* __restrict__ XS, const float* __restrict__ MX,
    const unsigned short* __restrict__ EqS, const unsigned short* __restrict__ EkS,
    const unsigned short* __restrict__ EvS,
    const float* __restrict__ bq, const float* __restrict__ bk,
    const float* __restrict__ bv,
    unsigned short* __restrict__ AS, unsigned short* __restrict__ VS)
{
  int t = threadIdx.x;
  int w = t >> 6, lane = t & 63;
  int mt = blockIdx.x >> 2, h = blockIdx.x & 3;
  int row0 = mt * 16;

  __shared__ float fbuf[3][16][65];          // ~12.5 KB (pad 65)

  // --- issue ALL global loads first: 8 A-frags + 24 B-frags + row maxes ---
  const half8* XS8 = (const half8*)(XS + mt * 4096);
  half8 afrag[8];
#pragma unroll
  for (int kk = 0; kk < 8; ++kk)
    afrag[kk] = XS8[kk * 64 + lane];

  int bb = ((h * 64 + w * 16 + (lane & 15)) << 2) + (lane >> 4);
  const half8* BQ = (const half8*)EqS;
  const half8* BK = (const half8*)EkS;
  const half8* BV = (const half8*)EvS;
  half8 bqf[8], bkf[8], bvf[8];
#pragma unroll
  for (int kk = 0; kk < 8; ++kk) {
    bqf[kk] = BQ[kk * 1024 + bb];
    bkf[kk] = BK[kk * 1024 + bb];
    bvf[kk] = BV[kk * 1024 + bb];
  }

  float mx[4];
#pragma unroll
  for (int i = 0; i < 4; ++i) mx[i] = MX[row0 + 4 * w + i];

  // --- MFMA main loop: everything already in registers ---
  floatx4 accq = {0.f, 0.f, 0.f, 0.f};
  floatx4 acck = {0.f, 0.f, 0.f, 0.f};
  floatx4 accv = {0.f, 0.f, 0.f, 0.f};
#pragma unroll
  for (int kk = 0; kk < 8; ++kk) {
    accq = __builtin_amdgcn_mfma_f32_16x16x32_f16(afrag[kk], bqf[kk], accq, 0, 0, 0);
    acck = __builtin_amdgcn_mfma_f32_16x16x32_f16(afrag[kk], bkf[kk], acck, 0, 0, 0);
    accv = __builtin_amdgcn_mfma_f32_16x16x32_f16(afrag[kk], bvf[kk], accv, 0, 0, 0);
  }

  // --- C frags -> LDS (D: col=lane&15, row=4*(lane>>4)+reg) ---
  {
    int c = w * 16 + (lane & 15);
    int rb = (lane >> 4) * 4;
#pragma unroll
    for (int reg = 0; reg < 4; ++reg) {
      fbuf[0][rb + reg][c] = accq[reg];
      fbuf[1][rb + reg][c] = acck[reg];
      fbuf[2][rb + reg][c] = accv[reg];
    }
  }
  __syncthreads();

  // --- epilogue: wave w owns rows 4w..4w+3; lane = col (d) within head ---
  int cg = h * 64 + lane;
  float bqv = bq[cg], bkv = bk[cg], bvv = bv[cg];
  int b = row0 >> 6;
  int mt16 = (row0 >> 4) & 3;
  size_t asBase = (size_t)(((b * 4 + mt16) * 4) + h) * 1024
                + (lane >> 5) * 512 + ((lane >> 3) & 3) * 128 + (lane & 7);
#pragma unroll
  for (int i = 0; i < 4; ++i) {
    int r = 4 * w + i;
    float Mr = mx[i];
    float qv = Mr + __logf(fbuf[0][r][lane]) + bqv;
    float kv = Mr + __logf(fbuf[1][r][lane]) + bkv;
    float vv = Mr + __logf(fbuf[2][r][lane]) + bvv;
    // v -> B-frag-swizzled VS: k = d = mt16*16 + r, n = cg
    int d = mt16 * 16 + r;
    VS[(size_t)(b * 2 + (d >> 5)) * 8192 + cg * 32 + ((d >> 3) & 3) * 8 + (d & 7)]
        = f2h(vv);
    // softmax of q+k over the 64-lane head segment
    float s = qv + kv;
    float sm = s;
#pragma unroll
    for (int off = 32; off > 0; off >>= 1) sm = fmaxf(sm, __shfl_xor(sm, off));
    float ex = __expf(s - sm);
    float den = ex;
#pragma unroll
    for (int off = 32; off > 0; off >>= 1) den += __shfl_xor(den, off);
    // attn -> A-frag-swizzled AS: m = r, k = lane
    AS[asBase + r * 8] = f2h(ex / den);
  }
}

// ---------------------------------------------------------------------------
// Kernel C: fused MFMA attn@v + output tropical linear.
// grid 256 = (b, mt, half): block = 4 waves. Each block does the FULL
// attn@v (wave w = head w, 8 MFMAs — duplicated across the 2 halves) and
// full rowmax/exp, then the o-linear for its 128-col half only
// (16 MFMAs/wave instead of 32). Doubles CU coverage, shortens the chain.
// ---------------------------------------------------------------------------
__global__ __launch_bounds__(256, 2) void avo_mfma_kernel(
    const unsigned short* __restrict__ AS, const unsigned short* __restrict__ VS,
    const unsigned short* __restrict__ EoS, const float* __restrict__ bo,
    float* __restrict__ y)
{
  int t = threadIdx.x, w = t >> 6, lane = t & 63;
  int blk = blockIdx.x;
  int b = blk >> 3, mt = (blk >> 1) & 3, hf = blk & 1;
  int row0 = b * 64 + mt * 16;
  int q = lane >> 4, nl = lane & 15;

  __shared__ float obuf[16][260];            // 16.6 KB (pad 260)
  __shared__ unsigned short easwz[8 * 512];  // 8 KB
  __shared__ float Mrow[16];

  // ---- attn@v (full 256 cols): wave w = head w ----
  const half8* AS8 = (const half8*)(AS + (size_t)(((b * 4 + mt) * 4) + w) * 1024);
  const half8* VS8 = (const half8*)VS;
  half8 af0 = AS8[lane], af1 = AS8[64 + lane];
  floatx4 acc[4];
#pragma unroll
  for (int nt = 0; nt < 4; ++nt) acc[nt] = (floatx4){0.f, 0.f, 0.f, 0.f};
#pragma unroll
  for (int nt = 0; nt < 4; ++nt) {
    int n = w * 64 + nt * 16 + nl;
    half8 b0 = VS8[(size_t)(b * 2 + 0) * 1024 + n * 4 + q];
    half8 b1 = VS8[(size_t)(b * 2 + 1) * 1024 + n * 4 + q];
    acc[nt] = __builtin_amdgcn_mfma_f32_16x16x32_f16(af0, b0, acc[nt], 0, 0, 0);
    acc[nt] = __builtin_amdgcn_mfma_f32_16x16x32_f16(af1, b1, acc[nt], 0, 0, 0);
  }
  int rb = q * 4;
#pragma unroll
  for (int nt = 0; nt < 4; ++nt)
#pragma unroll
    for (int reg = 0; reg < 4; ++reg)
      obuf[rb + reg][w * 64 + nt * 16 + nl] = acc[nt][reg];
  __syncthreads();

  // ---- rowmax + exp + A-frag swizzle for the o-linear (full row) ----
#pragma unroll
  for (int i = 0; i < 4; ++i) {
    int r = 4 * w + i;
    float4 o4 = *(const float4*)&obuf[r][lane * 4];
    float m = fmaxf(fmaxf(o4.x, o4.y), fmaxf(o4.z, o4.w));
#pragma unroll
    for (int off = 32; off > 0; off >>= 1) m = fmaxf(m, __shfl_xor(m, off));
    ushort4 pk;
    pk.x = f2h(__expf(o4.x - m));
    pk.y = f2h(__expf(o4.y - m));
    pk.z = f2h(__expf(o4.z - m));
    pk.w = f2h(__expf(o4.w - m));
    int k0 = lane * 4;
    int idx = (k0 >> 5) * 512 + ((k0 >> 3) & 3) * 128 + r * 8 + (k0 & 7);
    *(ushort4*)&easwz[idx] = pk;
    if (lane == 0) Mrow[r] = m;
  }
  __syncthreads();

  // ---- o-linear MFMA: this half's 128 cols; wave w -> 32 cols ----
  half8 af2[8];
#pragma unroll
  for (int kk = 0; kk < 8; ++kk)
    af2[kk] = *(const half8*)&easwz[kk * 512 + lane * 8];
  const half8* BO = (const half8*)EoS;
  floatx4 acc2[2];
  acc2[0] = (floatx4){0.f, 0.f, 0.f, 0.f};
  acc2[1] = (floatx4){0.f, 0.f, 0.f, 0.f};
#pragma unroll
  for (int kk = 0; kk < 8; ++kk) {
#pragma unroll
    for (int nt = 0; nt < 2; ++nt) {
      int n = hf * 128 + w * 32 + nt * 16 + nl;
      acc2[nt] = __builtin_amdgcn_mfma_f32_16x16x32_f16(
          af2[kk], BO[kk * 1024 + n * 4 + q], acc2[nt], 0, 0, 0);
    }
  }
#pragma unroll
  for (int nt = 0; nt < 2; ++nt)
#pragma unroll
    for (int reg = 0; reg < 4; ++reg)
      obuf[rb + reg][hf * 128 + w * 32 + nt * 16 + nl] = acc2[nt][reg];
  __syncthreads();

  // ---- epilogue: log + bias, float2 stores over this half's 128 cols ----
  int c0 = hf * 128 + lane * 2;
  float2 bo2 = *(const float2*)&bo[c0];
#pragma unroll
  for (int i = 0; i < 4; ++i) {
    int r = 4 * w + i;
    float2 f2 = *(const float2*)&obuf[r][c0];
    float M = Mrow[r];
    float2 y2;
    y2.x = M + __logf(f2.x) + bo2.x;
    y2.y = M + __logf(f2.y) + bo2.y;
    *(float2*)&y[(size_t)(row0 + r) * ED + c0] = y2;
  }
}

// ---------------------------------------------------------------------------
extern "C" void kernel_launch(void* const* d_in, const int* in_sizes, int n_in,
                              void* d_out, int out_size, void* d_ws, size_t ws_size,
                              hipStream_t stream) {
  const float* x  = (const float*)d_in[0];
  const float* Wq = (const float*)d_in[1];
  const float* bq = (const float*)d_in[2];
  const float* Wk = (const float*)d_in[3];
  const float* bk = (const float*)d_in[4];
  const float* Wv = (const float*)d_in[5];
  const float* bv = (const float*)d_in[6];
  const float* Wo = (const float*)d_in[7];
  const float* bo = (const float*)d_in[8];
  float* y = (float*)d_out;

  // ws (bytes): EqS/EkS/EvS/EoS 128K each | AS 1M | VS 1M | XS 1M | MX 8K
  char* ws = (char*)d_ws;
  unsigned short* EqS = (unsigned short*)(ws);
  unsigned short* EkS = (unsigned short*)(ws + 131072);
  unsigned short* EvS = (unsigned short*)(ws + 262144);
  unsigned short* EoS = (unsigned short*)(ws + 393216);
  unsigned short* AS  = (unsigned short*)(ws + 524288);
  unsigned short* VS  = (unsigned short*)(ws + 524288 + 1048576);
  unsigned short* XS  = (unsigned short*)(ws + 524288 + 2097152);
  float*          MX  = (float*)(ws + 524288 + 3145728);

  prep_kernel<<<256, 256, 0, stream>>>(x, Wq, Wk, Wv, Wo,
                                       EqS, EkS, EvS, EoS, XS, MX);
  qkv_mfma_kernel<<<512, 256, 0, stream>>>(XS, MX, EqS, EkS, EvS, bq, bk, bv,
                                           AS, VS);
  avo_mfma_kernel<<<256, 256, 0, stream>>>(AS, VS, EoS, bo, y);
}